// Round 2
// baseline (13634.052 us; speedup 1.0000x reference)
//
#include <hip/hip_runtime.h>
#include <cstdint>
#include <cstddef>

// LSTM B=128 T=512 I=H=1024. fp32 in/out, bf16 MFMA internally.
//  pack_w     : W fp32 [K][H] -> bf16 [jc][k], jc = jh*4+gate (gate-interleaved)
//  convert_x  : x fp32 -> bf16 rows r = b*Tcc+tc
//  gemm_xproj : xp[tc][b][jc] = xb @ Winp + bias (bias = b_x+b_h)
//  lstm_recur : persistent cooperative kernel; Tcc steps with internal grid
//               barrier. W_h resident in VGPRs (128/thread), c resident in
//               VGPRs, h broadcast via global bf16 double-buffer + LDS stage.
// Output: d_out = [h (128x1024) | c (128x1024)] fp32, written on final step.

#define B_  128
#define T_  512
#define I_  1024
#define H_  1024
#define G4_ 4096

typedef __attribute__((ext_vector_type(8))) short short8;   // 8 bf16
typedef __attribute__((ext_vector_type(4))) float f32x4;

struct GBar { unsigned cnt[256]; unsigned root[32]; unsigned gen[32]; };

static __device__ __forceinline__ unsigned short f2bf(float f) {
    unsigned u = __builtin_bit_cast(unsigned, f);
    u += 0x7fffu + ((u >> 16) & 1u);          // RNE
    return (unsigned short)(u >> 16);
}
static __device__ __forceinline__ float sigm(float x) {
    return 1.0f / (1.0f + exp2f(-1.4426950408889634f * x));
}
static __device__ __forceinline__ float tanh_(float x) {
    float e = exp2f(2.8853900817779268f * x);  // exp(2x)
    return 1.0f - 2.0f / (e + 1.0f);
}
static __device__ __forceinline__ f32x4 mfma16(short8 a, short8 b, f32x4 c) {
    return __builtin_amdgcn_mfma_f32_16x16x32_bf16(a, b, c, 0, 0, 0);
}

// ---- pack one 1024x1024 fp32 weight into bf16 [jc][k] for gate g ----
__global__ __launch_bounds__(256) void pack_w(const float* __restrict__ W,
                                              unsigned short* __restrict__ outBt,
                                              int g) {
    __shared__ float tile[64][65];
    const int tid = threadIdx.x;
    const int k0 = blockIdx.y * 64;
    const int j0 = blockIdx.x * 64;
    {
        const int r  = tid >> 2;
        const int c0 = (tid & 3) * 16;
        const float* src = W + (size_t)(k0 + r) * H_ + j0 + c0;
        #pragma unroll
        for (int q = 0; q < 4; ++q) {
            float4 v = *(const float4*)(src + q * 4);
            tile[r][c0 + q*4 + 0] = v.x;
            tile[r][c0 + q*4 + 1] = v.y;
            tile[r][c0 + q*4 + 2] = v.z;
            tile[r][c0 + q*4 + 3] = v.w;
        }
    }
    __syncthreads();
    {
        const int jl   = tid >> 2;
        const int kseg = (tid & 3) * 16;
        unsigned short* orow = outBt + ((size_t)(j0 + jl) * 4 + g) * 1024 + (k0 + kseg);
        #pragma unroll
        for (int q = 0; q < 16; q += 4) {
            ushort4 u;
            u.x = f2bf(tile[kseg + q + 0][jl]);
            u.y = f2bf(tile[kseg + q + 1][jl]);
            u.z = f2bf(tile[kseg + q + 2][jl]);
            u.w = f2bf(tile[kseg + q + 3][jl]);
            *(ushort4*)(orow + q) = u;
        }
    }
}

__global__ __launch_bounds__(256) void pack_bias(
    const float* b0x, const float* b0h, const float* b1x, const float* b1h,
    const float* b2x, const float* b2h, const float* b3x, const float* b3h,
    float* __restrict__ out) {
    int jc = blockIdx.x * 256 + threadIdx.x;
    int g = jc & 3, jh = jc >> 2;
    const float* bx = (g == 0) ? b0x : (g == 1) ? b1x : (g == 2) ? b2x : b3x;
    const float* bh = (g == 0) ? b0h : (g == 1) ? b1h : (g == 2) ? b2h : b3h;
    out[jc] = bx[jh] + bh[jh];
}

__global__ __launch_bounds__(256) void convert_x(const float* __restrict__ x,
                                                 unsigned short* __restrict__ xb,
                                                 int t0, int Tcc) {
    int e = blockIdx.x * 256 + threadIdx.x;
    int i = (e & 127) << 3;
    int r = e >> 7;
    int b = r / Tcc, tc = r - b * Tcc;
    const float* s = x + (size_t)(b * T_ + t0 + tc) * I_ + i;
    float4 v0 = *(const float4*)s;
    float4 v1 = *(const float4*)(s + 4);
    ushort4 u0; u0.x = f2bf(v0.x); u0.y = f2bf(v0.y); u0.z = f2bf(v0.z); u0.w = f2bf(v0.w);
    ushort4 u1; u1.x = f2bf(v1.x); u1.y = f2bf(v1.y); u1.z = f2bf(v1.z); u1.w = f2bf(v1.w);
    unsigned short* d = xb + (size_t)r * I_ + i;
    *(ushort4*)d = u0;
    *(ushort4*)(d + 4) = u1;
}

// ---- xp = xb @ Winp + bias. grid (32, 2*Tcc); 4 waves; wave: 64r x 32c ----
__global__ __launch_bounds__(256) void gemm_xproj(
    const unsigned short* __restrict__ A,
    const unsigned short* __restrict__ Bt,
    const float* __restrict__ bias,
    float* __restrict__ xp,
    int Tcc) {
    const int tid = threadIdx.x;
    const int w = tid >> 6, l = tid & 63;
    const int l15 = l & 15, hi = l >> 4;
    const int row0 = blockIdx.y * 64;
    const int col0 = blockIdx.x * 128 + w * 32;
    const int k0 = hi * 8;
    f32x4 acc[4][2] = {};
    const unsigned short* a0 = A  + (size_t)(row0 + l15) * 1024 + k0;
    const unsigned short* b0 = Bt + (size_t)(col0 + l15) * 1024 + k0;
    for (int ks = 0; ks < 1024; ks += 32) {
        short8 a[4], bb[2];
        #pragma unroll
        for (int mi = 0; mi < 4; ++mi) a[mi]  = *(const short8*)(a0 + (size_t)mi * 16 * 1024 + ks);
        #pragma unroll
        for (int ni = 0; ni < 2; ++ni) bb[ni] = *(const short8*)(b0 + (size_t)ni * 16 * 1024 + ks);
        #pragma unroll
        for (int mi = 0; mi < 4; ++mi)
            #pragma unroll
            for (int ni = 0; ni < 2; ++ni)
                acc[mi][ni] = mfma16(a[mi], bb[ni], acc[mi][ni]);
    }
    #pragma unroll
    for (int mi = 0; mi < 4; ++mi) {
        #pragma unroll
        for (int ni = 0; ni < 2; ++ni) {
            int colg = col0 + ni * 16 + l15;
            float bs = bias[colg];
            #pragma unroll
            for (int j = 0; j < 4; ++j) {
                int r = row0 + mi * 16 + hi * 4 + j;
                int b = r / Tcc, tc = r - b * Tcc;
                xp[(size_t)(tc * 128 + b) * G4_ + colg] = acc[mi][ni][j] + bs;
            }
        }
    }
}

// ---- persistent recurrence: grid 256 x 256 threads, cooperative ----
// block: rows [rb*32,+32) x packed cols [cb*64,+64); wave (wc,kh):
// cols wc*32..+32, K-half kh*512..+512. W-frags resident: wf[32] (128 VGPR).
__global__ __launch_bounds__(256, 1) void lstm_recur(
    const unsigned short* __restrict__ Whp,
    const float* __restrict__ xp,
    unsigned short* __restrict__ hbA,
    unsigned short* __restrict__ hbB,
    float* __restrict__ cbuf,
    float* __restrict__ outp,
    GBar* __restrict__ bar,
    int Tcc, int t0, int is_last_chunk) {
    __shared__ uint4 hlds4[4096];            // 64 KB staged h (XOR-swizzled)
    __shared__ float gl[32][68];             // gate merge buffer
    char* hlds = (char*)hlds4;

    const int tid = threadIdx.x;
    const int w = tid >> 6, l = tid & 63;
    const int l15 = l & 15, hi = l >> 4;
    const int wc = w & 1, kh = w >> 1;
    const int cb = blockIdx.x & 63, rb = blockIdx.x >> 6;
    const int row0 = rb * 32;

    // resident weights: 2 col-tiles x 16 k-steps (of this wave's K-half)
    short8 wf[32];
    {
        const unsigned short* wb = Whp + (size_t)(cb * 64 + wc * 32 + l15) * 1024
                                       + kh * 512 + hi * 8;
        #pragma unroll
        for (int ci = 0; ci < 2; ++ci)
            #pragma unroll
            for (int ks = 0; ks < 16; ++ks)
                wf[ci * 16 + ks] = *(const short8*)(wb + ci * 16 * 1024 + ks * 32);
    }
    // per-thread cell state: items q = tid*2+s -> (row, jh)
    const int q0 = tid * 2;
    const int prow0 = q0 >> 4,       pjh0 = q0 & 15;
    const int prow1 = (q0 + 1) >> 4, pjh1 = (q0 + 1) & 15;
    float creg0 = cbuf[(size_t)(row0 + prow0) * H_ + cb * 16 + pjh0];
    float creg1 = cbuf[(size_t)(row0 + prow1) * H_ + cb * 16 + pjh1];

    unsigned short* hb[2] = { hbA, hbB };

    for (int st = 0; st < Tcc; ++st) {
        const int t = t0 + st;
        const unsigned short* hin = hb[t & 1];
        unsigned short* hout = hb[(t + 1) & 1];

        // prefetch xp (independent of h)
        const float4* xr = (const float4*)(xp + (size_t)st * 128 * G4_);
        float4 xv0 = xr[(size_t)(row0 + prow0) * 1024 + cb * 16 + pjh0];
        float4 xv1 = xr[(size_t)(row0 + prow1) * 1024 + cb * 16 + pjh1];

        // stage h rows [row0,+32) into LDS, swizzle byte ^= ((row&7)<<4)
        {
            const uint4* src = (const uint4*)(hin + (size_t)row0 * H_);
            #pragma unroll
            for (int i = 0; i < 16; ++i) {
                int g = i * 256 + tid;               // 16B granule index
                uint4 v = src[g];
                int off = (g * 16) ^ (((g >> 7) & 7) << 4);
                *(uint4*)(hlds + off) = v;
            }
        }
        __syncthreads();

        f32x4 acc00 = {}, acc01 = {}, acc10 = {}, acc11 = {};
        {
            const int kbyte = kh * 1024 + hi * 16;
            const int b0 = l15 * 2048 + kbyte;
            const int b1 = (16 + l15) * 2048 + kbyte;
            const int sw = (l15 & 7) << 4;
            #pragma unroll
            for (int ks = 0; ks < 16; ++ks) {
                short8 a0 = *(const short8*)(hlds + ((b0 + ks * 64) ^ sw));
                short8 a1 = *(const short8*)(hlds + ((b1 + ks * 64) ^ sw));
                acc00 = mfma16(a0, wf[ks],      acc00);
                acc10 = mfma16(a1, wf[ks],      acc10);
                acc01 = mfma16(a0, wf[16 + ks], acc01);
                acc11 = mfma16(a1, wf[16 + ks], acc11);
            }
        }
        // merge K-halves through LDS: kh0 writes, kh1 adds
        if (kh == 0) {
            #pragma unroll
            for (int j = 0; j < 4; ++j) {
                gl[hi * 4 + j][wc * 32 + l15]       = acc00[j];
                gl[16 + hi * 4 + j][wc * 32 + l15]  = acc10[j];
                gl[hi * 4 + j][wc * 32 + 16 + l15]      = acc01[j];
                gl[16 + hi * 4 + j][wc * 32 + 16 + l15] = acc11[j];
            }
        }
        __syncthreads();
        if (kh == 1) {
            #pragma unroll
            for (int j = 0; j < 4; ++j) {
                gl[hi * 4 + j][wc * 32 + l15]       += acc00[j];
                gl[16 + hi * 4 + j][wc * 32 + l15]  += acc10[j];
                gl[hi * 4 + j][wc * 32 + 16 + l15]      += acc01[j];
                gl[16 + hi * 4 + j][wc * 32 + 16 + l15] += acc11[j];
            }
        }
        __syncthreads();

        // pointwise cell update (2 items/thread), c stays in registers
        #pragma unroll
        for (int s = 0; s < 2; ++s) {
            int row = s ? prow1 : prow0;
            int jh  = s ? pjh1  : pjh0;
            float4 xv = s ? xv1 : xv0;
            float gi = gl[row][jh * 4 + 0] + xv.x;
            float gf = gl[row][jh * 4 + 1] + xv.y;
            float gg = gl[row][jh * 4 + 2] + xv.z;
            float go = gl[row][jh * 4 + 3] + xv.w;
            float it = sigm(gi), ft = sigm(gf), gt = tanh_(gg), ot = sigm(go);
            float co = s ? creg1 : creg0;
            float cn = ft * co + it * gt;
            float hn = ot * tanh_(cn);
            if (s) creg1 = cn; else creg0 = cn;
            size_t oidx = (size_t)(row0 + row) * H_ + cb * 16 + jh;
            hout[oidx] = f2bf(hn);
            if (is_last_chunk && st == Tcc - 1) {
                outp[oidx] = hn;
                outp[(size_t)B_ * H_ + oidx] = cn;
            }
        }

        // grid barrier (not after the final step of this chunk)
        if (st != Tcc - 1) {
            __syncthreads();                 // drains vmcnt: h stores complete
            if (tid == 0) {
                __threadfence();             // release (L2 writeback)
                int g = blockIdx.x & 7;
                unsigned old = __hip_atomic_fetch_add(&bar->cnt[g * 32], 1u,
                                 __ATOMIC_RELEASE, __HIP_MEMORY_SCOPE_AGENT);
                if (old == (unsigned)(st * 32 + 31)) {
                    unsigned r = __hip_atomic_fetch_add(&bar->root[0], 1u,
                                 __ATOMIC_ACQ_REL, __HIP_MEMORY_SCOPE_AGENT);
                    if (r == (unsigned)(st * 8 + 7))
                        __hip_atomic_store(&bar->gen[0], (unsigned)(st + 1),
                                 __ATOMIC_RELEASE, __HIP_MEMORY_SCOPE_AGENT);
                }
                while (__hip_atomic_load(&bar->gen[0], __ATOMIC_RELAXED,
                         __HIP_MEMORY_SCOPE_AGENT) <= (unsigned)st)
                    __builtin_amdgcn_s_sleep(1);
                __threadfence();             // acquire (invalidate stale lines)
            }
            __syncthreads();
        }
    }
    cbuf[(size_t)(row0 + prow0) * H_ + cb * 16 + pjh0] = creg0;
    cbuf[(size_t)(row0 + prow1) * H_ + cb * 16 + pjh1] = creg1;
}

extern "C" void kernel_launch(void* const* d_in, const int* in_sizes, int n_in,
                              void* d_out, int out_size, void* d_ws, size_t ws_size,
                              hipStream_t stream) {
    const float* x = (const float*)d_in[0];
    const float* Wx[4] = {(const float*)d_in[1], (const float*)d_in[3],
                          (const float*)d_in[5], (const float*)d_in[7]};
    const float* Wh[4] = {(const float*)d_in[2], (const float*)d_in[4],
                          (const float*)d_in[6], (const float*)d_in[8]};
    const float* bx[4] = {(const float*)d_in[9],  (const float*)d_in[11],
                          (const float*)d_in[13], (const float*)d_in[15]};
    const float* bh[4] = {(const float*)d_in[10], (const float*)d_in[12],
                          (const float*)d_in[14], (const float*)d_in[16]};

    char* p = (char*)d_ws;
    auto take = [&](size_t bytes) {
        char* q = p; p += (bytes + 255) & ~(size_t)255; return q;
    };
    unsigned short* Winp = (unsigned short*)take((size_t)G4_ * 1024 * 2);
    unsigned short* Whp  = (unsigned short*)take((size_t)G4_ * 1024 * 2);
    float*          bias = (float*)take(G4_ * 4);
    unsigned short* hb0  = (unsigned short*)take((size_t)B_ * H_ * 2);
    unsigned short* hb1  = (unsigned short*)take((size_t)B_ * H_ * 2);
    float*          cbuf = (float*)take((size_t)B_ * H_ * 4);
    GBar*           bar  = (GBar*)take(sizeof(GBar));
    size_t fixed = (size_t)(p - (char*)d_ws);
    size_t per = (size_t)B_ * I_ * 2 + (size_t)B_ * G4_ * 4 + 512;
    size_t avail = ws_size > fixed ? ws_size - fixed : 0;
    int Tc = (int)(avail / per);
    if (Tc > T_) Tc = T_;
    if (Tc < 1) Tc = 1;
    unsigned short* xb  = (unsigned short*)take((size_t)Tc * B_ * I_ * 2);
    float*          xpc = (float*)take((size_t)Tc * B_ * G4_ * 4);

    for (int g = 0; g < 4; ++g) {
        pack_w<<<dim3(16, 16), 256, 0, stream>>>(Wx[g], Winp, g);
        pack_w<<<dim3(16, 16), 256, 0, stream>>>(Wh[g], Whp, g);
    }
    pack_bias<<<16, 256, 0, stream>>>(bx[0], bh[0], bx[1], bh[1],
                                      bx[2], bh[2], bx[3], bh[3], bias);
    hipMemsetAsync(hb0, 0, (size_t)B_ * H_ * 2, stream);
    hipMemsetAsync(cbuf, 0, (size_t)B_ * H_ * 4, stream);

    for (int t0 = 0; t0 < T_; t0 += Tc) {
        int Tcc = (T_ - t0 < Tc) ? (T_ - t0) : Tc;
        int last = (t0 + Tcc >= T_) ? 1 : 0;
        convert_x<<<Tcc * 64, 256, 0, stream>>>(x, xb, t0, Tcc);
        gemm_xproj<<<dim3(32, 2 * Tcc), 256, 0, stream>>>(xb, Winp, bias, xpc, Tcc);
        hipMemsetAsync(bar, 0, sizeof(GBar), stream);

        void* kargs[10];
        const unsigned short* WhpC = Whp;
        const float* xpC = xpc;
        float* outF = (float*)d_out;
        kargs[0] = (void*)&WhpC;  kargs[1] = (void*)&xpC;
        kargs[2] = (void*)&hb0;   kargs[3] = (void*)&hb1;
        kargs[4] = (void*)&cbuf;  kargs[5] = (void*)&outF;
        kargs[6] = (void*)&bar;   kargs[7] = (void*)&Tcc;
        kargs[8] = (void*)&t0;    kargs[9] = (void*)&last;
        hipError_t e = hipLaunchCooperativeKernel(
            reinterpret_cast<void*>(lstm_recur), dim3(256), dim3(256),
            kargs, 0, stream);
        if (e != hipSuccess) {
            // 256 blocks x 74KB LDS always co-resident (capacity 2/CU) -> safe
            lstm_recur<<<256, 256, 0, stream>>>(Whp, xpc, hb0, hb1, cbuf,
                                                (float*)d_out, bar, Tcc, t0, last);
        }
    }
}

// Round 3
// 3956.902 us; speedup vs baseline: 3.4456x; 3.4456x over previous
//
#include <hip/hip_runtime.h>
#include <cstdint>
#include <cstddef>

// LSTM B=128 T=512 I=H=1024. fp32 in/out, bf16 MFMA internally.
// Recurrence: 8 independent groups (16 batch rows each) x 32 blocks
// (128 packed gate-cols each, W_h slice resident in VGPRs). No grid
// barrier: h published per step into a 0xFF-sentinel ring via agent-scope
// 8B atomic exchange; consumers poll with relaxed agent atomic loads
// (RMW fallback for guaranteed progress). bf16 0xFFFF (NaN) never occurs
// as real h data (|h|<1, finite), so data availability is the flag.

#define B_  128
#define T_  512
#define I_  1024
#define H_  1024
#define G4_ 4096
#define SLOTG 32768ull   // u64 granules per h slot (128*1024*2B / 8)

typedef __attribute__((ext_vector_type(8))) short short8;   // 8 bf16
typedef __attribute__((ext_vector_type(4))) float f32x4;
typedef unsigned long long u64;

static __device__ __forceinline__ unsigned short f2bf(float f) {
    unsigned u = __builtin_bit_cast(unsigned, f);
    u += 0x7fffu + ((u >> 16) & 1u);          // RNE (finite inputs)
    return (unsigned short)(u >> 16);
}
static __device__ __forceinline__ float bf2f(unsigned short s) {
    unsigned u = (unsigned)s << 16;
    return __builtin_bit_cast(float, u);
}
static __device__ __forceinline__ float sigm(float x) {
    return 1.0f / (1.0f + exp2f(-1.4426950408889634f * x));
}
static __device__ __forceinline__ float tanh_(float x) {
    float e = exp2f(2.8853900817779268f * x);  // exp(2x)
    return 1.0f - 2.0f / (e + 1.0f);
}
static __device__ __forceinline__ f32x4 mfma16(short8 a, short8 b, f32x4 c) {
    return __builtin_amdgcn_mfma_f32_16x16x32_bf16(a, b, c, 0, 0, 0);
}
// true if any u16 lane of v is 0xFFFF (the sentinel)
static __device__ __forceinline__ bool hasff(u64 v) {
    u64 x = ~v;
    return ((x - 0x0001000100010001ull) & ~x & 0x8000800080008000ull) != 0ull;
}

// ---- pack one 1024x1024 fp32 weight into bf16 [jc][k] for gate g ----
__global__ __launch_bounds__(256) void pack_w(const float* __restrict__ W,
                                              unsigned short* __restrict__ outBt,
                                              int g) {
    __shared__ float tile[64][65];
    const int tid = threadIdx.x;
    const int k0 = blockIdx.y * 64;
    const int j0 = blockIdx.x * 64;
    {
        const int r  = tid >> 2;
        const int c0 = (tid & 3) * 16;
        const float* src = W + (size_t)(k0 + r) * H_ + j0 + c0;
        #pragma unroll
        for (int q = 0; q < 4; ++q) {
            float4 v = *(const float4*)(src + q * 4);
            tile[r][c0 + q*4 + 0] = v.x;
            tile[r][c0 + q*4 + 1] = v.y;
            tile[r][c0 + q*4 + 2] = v.z;
            tile[r][c0 + q*4 + 3] = v.w;
        }
    }
    __syncthreads();
    {
        const int jl   = tid >> 2;
        const int kseg = (tid & 3) * 16;
        unsigned short* orow = outBt + ((size_t)(j0 + jl) * 4 + g) * 1024 + (k0 + kseg);
        #pragma unroll
        for (int q = 0; q < 16; q += 4) {
            ushort4 u;
            u.x = f2bf(tile[kseg + q + 0][jl]);
            u.y = f2bf(tile[kseg + q + 1][jl]);
            u.z = f2bf(tile[kseg + q + 2][jl]);
            u.w = f2bf(tile[kseg + q + 3][jl]);
            *(ushort4*)(orow + q) = u;
        }
    }
}

__global__ __launch_bounds__(256) void pack_bias(
    const float* b0x, const float* b0h, const float* b1x, const float* b1h,
    const float* b2x, const float* b2h, const float* b3x, const float* b3h,
    float* __restrict__ out) {
    int jc = blockIdx.x * 256 + threadIdx.x;
    int g = jc & 3, jh = jc >> 2;
    const float* bx = (g == 0) ? b0x : (g == 1) ? b1x : (g == 2) ? b2x : b3x;
    const float* bh = (g == 0) ? b0h : (g == 1) ? b1h : (g == 2) ? b2h : b3h;
    out[jc] = bx[jh] + bh[jh];
}

__global__ __launch_bounds__(256) void convert_x(const float* __restrict__ x,
                                                 unsigned short* __restrict__ xb,
                                                 int t0, int Tcc) {
    int e = blockIdx.x * 256 + threadIdx.x;
    int i = (e & 127) << 3;
    int r = e >> 7;
    int b = r / Tcc, tc = r - b * Tcc;
    const float* s = x + (size_t)(b * T_ + t0 + tc) * I_ + i;
    float4 v0 = *(const float4*)s;
    float4 v1 = *(const float4*)(s + 4);
    ushort4 u0; u0.x = f2bf(v0.x); u0.y = f2bf(v0.y); u0.z = f2bf(v0.z); u0.w = f2bf(v0.w);
    ushort4 u1; u1.x = f2bf(v1.x); u1.y = f2bf(v1.y); u1.z = f2bf(v1.z); u1.w = f2bf(v1.w);
    unsigned short* d = xb + (size_t)r * I_ + i;
    *(ushort4*)d = u0;
    *(ushort4*)(d + 4) = u1;
}

// ---- xp(bf16) = xb @ Winp + bias. grid (16, 2*Tcc); 4 waves: 64r x 64c ----
__global__ __launch_bounds__(256) void gemm_xproj(
    const unsigned short* __restrict__ A,
    const unsigned short* __restrict__ Bt,
    const float* __restrict__ bias,
    unsigned short* __restrict__ xp,           // [Tcc][128][4096] bf16
    int Tcc) {
    const int tid = threadIdx.x;
    const int w = tid >> 6, l = tid & 63;
    const int l15 = l & 15, hi = l >> 4;
    const int row0 = blockIdx.y * 64;
    const int col0 = blockIdx.x * 256 + w * 64;
    const int k0 = hi * 8;
    f32x4 acc[4][4] = {};
    const unsigned short* a0 = A  + (size_t)(row0 + l15) * 1024 + k0;
    const unsigned short* b0 = Bt + (size_t)(col0 + l15) * 1024 + k0;
    for (int ks = 0; ks < 1024; ks += 32) {
        short8 a[4], bb[4];
        #pragma unroll
        for (int mi = 0; mi < 4; ++mi) a[mi]  = *(const short8*)(a0 + (size_t)mi * 16 * 1024 + ks);
        #pragma unroll
        for (int ni = 0; ni < 4; ++ni) bb[ni] = *(const short8*)(b0 + (size_t)ni * 16 * 1024 + ks);
        #pragma unroll
        for (int mi = 0; mi < 4; ++mi)
            #pragma unroll
            for (int ni = 0; ni < 4; ++ni)
                acc[mi][ni] = mfma16(a[mi], bb[ni], acc[mi][ni]);
    }
    #pragma unroll
    for (int mi = 0; mi < 4; ++mi) {
        #pragma unroll
        for (int ni = 0; ni < 4; ++ni) {
            int colg = col0 + ni * 16 + l15;
            float bs = bias[colg];
            #pragma unroll
            for (int j = 0; j < 4; ++j) {
                int r = row0 + mi * 16 + hi * 4 + j;
                int b = r / Tcc, tc = r - b * Tcc;
                xp[(size_t)(tc * 128 + b) * G4_ + colg] = f2bf(acc[mi][ni][j] + bs);
            }
        }
    }
}

// ---- recurrence: grid 256 x 1024 threads. group = bx>>5 (16 batch rows),
// block owns packed cols [ (bx&31)*128, +128 ). No grid barrier. ----
__global__ __launch_bounds__(1024, 4) void lstm_recur(
    const unsigned short* __restrict__ Whp,
    const unsigned short* __restrict__ xp,     // [Tcc][128][4096] bf16
    u64* __restrict__ hring,                   // (Tcc+1) slots of 128x1024 bf16
    float* __restrict__ cbuf,                  // [128][1024] fp32 in/out
    float* __restrict__ outp,                  // d_out [h|c] fp32
    int Tcc, int is_last_chunk) {
    __shared__ char hlds[32768];               // h tile 16 x 2048B, XOR-swizzled
    __shared__ float gl[16][132];              // gate merge (fp32)
    __shared__ unsigned short hstage[16][32];  // h bf16 staging for publish

    const int tid = threadIdx.x;
    const int wv = tid >> 6, l = tid & 63;
    const int l15 = l & 15, hi = l >> 4;
    const int ct = wv & 7, kh = wv >> 3;       // col-tile, K-half
    const int grp = blockIdx.x >> 5;           // 0..7 -> rows 16*grp..+15
    const int cb  = blockIdx.x & 31;           // packed cols cb*128..+127
    const int row0 = grp * 16;

    // resident W_h slice: 16 ksteps x short8 = 64 VGPR
    short8 wf[16];
    {
        const unsigned short* wb = Whp + (size_t)(cb * 128 + ct * 16 + l15) * 1024
                                       + kh * 512 + hi * 8;
        #pragma unroll
        for (int ks = 0; ks < 16; ++ks) wf[ks] = *(const short8*)(wb + ks * 32);
    }

    // cell-state ownership: threads 0..511 -> (erow, ejh)
    const int erow = tid >> 5, ejh = tid & 31;
    float creg = 0.f;
    if (tid < 512) creg = cbuf[(size_t)(row0 + erow) * H_ + cb * 32 + ejh];

    // h-granule read mapping: thread loads 4 consecutive 8B granules of row wv
    const int gcol = (tid & 63) * 4;           // granule col in [0,256)

    for (int st = 0; st < Tcc; ++st) {
        // xp prefetch (independent of h)
        ushort4 xv = {0, 0, 0, 0};
        if (tid < 512)
            xv = *(const ushort4*)(xp + ((size_t)st * 128 + row0 + erow) * G4_
                                      + cb * 128 + ejh * 4);

        // poll + load this thread's 4 granules of h_t
        u64 g0, g1, g2, g3;
        {
            u64* rp = hring + (size_t)st * SLOTG + (size_t)(row0 + wv) * 256 + gcol;
            for (int it = 0; ; ++it) {
                if (it < 64) {
                    g0 = __hip_atomic_load(rp + 0, __ATOMIC_RELAXED, __HIP_MEMORY_SCOPE_AGENT);
                    g1 = __hip_atomic_load(rp + 1, __ATOMIC_RELAXED, __HIP_MEMORY_SCOPE_AGENT);
                    g2 = __hip_atomic_load(rp + 2, __ATOMIC_RELAXED, __HIP_MEMORY_SCOPE_AGENT);
                    g3 = __hip_atomic_load(rp + 3, __ATOMIC_RELAXED, __HIP_MEMORY_SCOPE_AGENT);
                } else {   // RMW: forced to coherence point, guarantees progress
                    g0 = __hip_atomic_fetch_add(rp + 0, 0ull, __ATOMIC_RELAXED, __HIP_MEMORY_SCOPE_AGENT);
                    g1 = __hip_atomic_fetch_add(rp + 1, 0ull, __ATOMIC_RELAXED, __HIP_MEMORY_SCOPE_AGENT);
                    g2 = __hip_atomic_fetch_add(rp + 2, 0ull, __ATOMIC_RELAXED, __HIP_MEMORY_SCOPE_AGENT);
                    g3 = __hip_atomic_fetch_add(rp + 3, 0ull, __ATOMIC_RELAXED, __HIP_MEMORY_SCOPE_AGENT);
                }
                if (!(hasff(g0) | hasff(g1) | hasff(g2) | hasff(g3))) break;
                __builtin_amdgcn_s_sleep(1);
            }
        }
        // stage to LDS, swizzle byte ^= ((row&7)<<4)
        {
            int base = wv * 2048 + gcol * 8;
            int sw = (wv & 7) << 4;
            *(u64*)(hlds + ((base +  0) ^ sw)) = g0;
            *(u64*)(hlds + ((base +  8) ^ sw)) = g1;
            *(u64*)(hlds + ((base + 16) ^ sw)) = g2;
            *(u64*)(hlds + ((base + 24) ^ sw)) = g3;
        }
        __syncthreads();

        // MFMA: 16 rows x 16 cols (this wave's col-tile), K-half kh
        f32x4 acc = {};
        {
            const int abase = l15 * 2048 + kh * 1024 + hi * 16;
            const int sw = (l15 & 7) << 4;
            #pragma unroll
            for (int ks = 0; ks < 16; ++ks) {
                short8 a = *(const short8*)(hlds + ((abase + ks * 64) ^ sw));
                acc = mfma16(a, wf[ks], acc);
            }
        }
        // merge K-halves through gl
        if (kh == 0) {
            #pragma unroll
            for (int j = 0; j < 4; ++j) gl[hi * 4 + j][ct * 16 + l15] = acc[j];
        }
        __syncthreads();
        if (kh == 1) {
            #pragma unroll
            for (int j = 0; j < 4; ++j) gl[hi * 4 + j][ct * 16 + l15] += acc[j];
        }
        __syncthreads();

        // pointwise cell update (threads 0..511, one (row, hcol) each)
        if (tid < 512) {
            float gi = gl[erow][ejh * 4 + 0] + bf2f(xv.x);
            float gf = gl[erow][ejh * 4 + 1] + bf2f(xv.y);
            float gg = gl[erow][ejh * 4 + 2] + bf2f(xv.z);
            float go = gl[erow][ejh * 4 + 3] + bf2f(xv.w);
            float it = sigm(gi), ft = sigm(gf), gt = tanh_(gg), ot = sigm(go);
            float cn = ft * creg + it * gt;
            float hn = ot * tanh_(cn);
            creg = cn;
            hstage[erow][ejh] = f2bf(hn);
            if (is_last_chunk && st == Tcc - 1) {
                size_t oidx = (size_t)(row0 + erow) * H_ + cb * 32 + ejh;
                outp[oidx] = hn;
                outp[(size_t)B_ * H_ + oidx] = cn;
            }
        }
        __syncthreads();
        // publish h_{t+1} slice: 128 x 8B atomic exchange (RMW -> at IF)
        if (tid < 128) {
            int prow = tid >> 3, seg = tid & 7;
            u64 hv = *(const u64*)(&hstage[prow][seg * 4]);
            u64* wp = hring + (size_t)(st + 1) * SLOTG
                            + (size_t)(row0 + prow) * 256 + cb * 8 + seg;
            (void)__hip_atomic_exchange(wp, hv, __ATOMIC_RELAXED, __HIP_MEMORY_SCOPE_AGENT);
        }
        // no barrier needed here: next write to hstage/gl is after stage-sync
    }
    if (tid < 512)
        cbuf[(size_t)(row0 + erow) * H_ + cb * 32 + ejh] = creg;
}

extern "C" void kernel_launch(void* const* d_in, const int* in_sizes, int n_in,
                              void* d_out, int out_size, void* d_ws, size_t ws_size,
                              hipStream_t stream) {
    const float* x = (const float*)d_in[0];
    const float* Wx[4] = {(const float*)d_in[1], (const float*)d_in[3],
                          (const float*)d_in[5], (const float*)d_in[7]};
    const float* Wh[4] = {(const float*)d_in[2], (const float*)d_in[4],
                          (const float*)d_in[6], (const float*)d_in[8]};
    const float* bx[4] = {(const float*)d_in[9],  (const float*)d_in[11],
                          (const float*)d_in[13], (const float*)d_in[15]};
    const float* bh[4] = {(const float*)d_in[10], (const float*)d_in[12],
                          (const float*)d_in[14], (const float*)d_in[16]};

    char* p = (char*)d_ws;
    auto take = [&](size_t bytes) {
        char* q = p; p += (bytes + 255) & ~(size_t)255; return q;
    };
    unsigned short* Winp = (unsigned short*)take((size_t)G4_ * 1024 * 2);
    unsigned short* Whp  = (unsigned short*)take((size_t)G4_ * 1024 * 2);
    float*          bias = (float*)take(G4_ * 4);
    float*          cbuf = (float*)take((size_t)B_ * H_ * 4);
    size_t fixed = (size_t)(p - (char*)d_ws);
    // per-timestep: xb bf16 + xp bf16 + one h ring slot
    size_t per = (size_t)B_ * I_ * 2 + (size_t)B_ * G4_ * 2 + SLOTG * 8 + 768;
    size_t avail = ws_size > fixed + SLOTG * 8 ? ws_size - fixed - SLOTG * 8 : 0;
    int Tc = (int)(avail / per);
    if (Tc > T_) Tc = T_;
    if (Tc < 1) Tc = 1;
    unsigned short* xb    = (unsigned short*)take((size_t)Tc * B_ * I_ * 2);
    unsigned short* xpc   = (unsigned short*)take((size_t)Tc * B_ * G4_ * 2);
    u64*            hring = (u64*)take((size_t)(Tc + 1) * SLOTG * 8);

    for (int g = 0; g < 4; ++g) {
        pack_w<<<dim3(16, 16), 256, 0, stream>>>(Wx[g], Winp, g);
        pack_w<<<dim3(16, 16), 256, 0, stream>>>(Wh[g], Whp, g);
    }
    pack_bias<<<16, 256, 0, stream>>>(bx[0], bh[0], bx[1], bh[1],
                                      bx[2], bh[2], bx[3], bh[3], bias);
    hipMemsetAsync(cbuf, 0, (size_t)B_ * H_ * 4, stream);

    int prev_last = -1;
    for (int t0 = 0; t0 < T_; t0 += Tc) {
        int Tcc = (T_ - t0 < Tc) ? (T_ - t0) : Tc;
        int last = (t0 + Tcc >= T_) ? 1 : 0;
        // slot 0 = carried h (zeros for first chunk)
        if (prev_last < 0)
            hipMemsetAsync(hring, 0, SLOTG * 8, stream);
        else
            hipMemcpyAsync(hring, hring + (size_t)prev_last * SLOTG,
                           SLOTG * 8, hipMemcpyDeviceToDevice, stream);
        // slots 1..Tcc = sentinel
        hipMemsetAsync(hring + SLOTG, 0xFF, (size_t)Tcc * SLOTG * 8, stream);
        convert_x<<<Tcc * 64, 256, 0, stream>>>(x, xb, t0, Tcc);
        gemm_xproj<<<dim3(16, 2 * Tcc), 256, 0, stream>>>(xb, Winp, bias, xpc, Tcc);
        lstm_recur<<<256, 1024, 0, stream>>>(Whp, xpc, hring, cbuf,
                                             (float*)d_out, Tcc, last);
        prev_last = Tcc;
    }
}